// Round 1
// baseline (842.187 us; speedup 1.0000x reference)
//
#include <hip/hip_runtime.h>
#include <math.h>

// Problem constants
#define Bn 16
#define Qn 64
#define Nn 16384
#define Dn 128
#define NT 128                  // n-tile per block
#define NTILES (Nn / NT)        // 128
#define KC 32                   // k-chunk (over D for K1, over n for K3)

// Output layout (concat in reference return order):
//   res_vector  [B,Q,D] at 0            (131072 floats)
//   prob_soft   [B,Q,N] at 131072       (16777216 floats)
//   prob_logits [B,Q,N] at 16908288     (16777216 floats)
#define RES_ELEMS  (Bn * Qn * Dn)
#define SOFT_OFF   (RES_ELEMS)
#define LOG_OFF    (RES_ELEMS + Bn * Qn * Nn)

#define NEGF (-3.4e38f)

// ---------------------------------------------------------------------------
// K1: logits = Q @ A^T for one (b, n-tile); write raw logits; masked per-tile
//     max / sumexp partials to workspace.
// Block: 256 threads = 16(ty, q-groups of 4) x 16(tx, n-groups of 8).
// ---------------------------------------------------------------------------
__global__ __launch_bounds__(256) void k_logits(
    const float* __restrict__ qv,      // [B,Q,D]
    const float* __restrict__ A,       // [B,N,D]
    const int*   __restrict__ nodeNum, // [B]
    float* __restrict__ logits,        // [B,Q,N]
    float* __restrict__ pmax,          // [B*Q, NTILES]
    float* __restrict__ psum)          // [B*Q, NTILES]
{
    const int b = blockIdx.y, tile = blockIdx.x;
    const int n0 = tile * NT;
    const int tid = threadIdx.x;
    const int tx = tid & 15, ty = tid >> 4;

    __shared__ float qs[Qn][KC + 1];   // 64 x 33
    __shared__ float as[NT][KC + 1];   // 128 x 33
    __shared__ float redm[Qn][17];
    __shared__ float reds[Qn][17];

    float acc[4][8];
#pragma unroll
    for (int i = 0; i < 4; i++)
#pragma unroll
        for (int j = 0; j < 8; j++) acc[i][j] = 0.f;

    const float* qb = qv + (size_t)b * Qn * Dn;
    const float* Ab = A  + (size_t)b * Nn * Dn + (size_t)n0 * Dn;

    for (int kk = 0; kk < Dn; kk += KC) {
        __syncthreads();
        // stage q chunk: 64 x 32 floats = 512 float4, 2 per thread
#pragma unroll
        for (int t = 0; t < 2; t++) {
            int idx = tid + t * 256;
            int row = idx >> 3, c = (idx & 7) * 4;
            float4 v = *(const float4*)(qb + row * Dn + kk + c);
            qs[row][c + 0] = v.x; qs[row][c + 1] = v.y;
            qs[row][c + 2] = v.z; qs[row][c + 3] = v.w;
        }
        // stage A chunk: 128 x 32 floats = 1024 float4, 4 per thread
#pragma unroll
        for (int t = 0; t < 4; t++) {
            int idx = tid + t * 256;
            int row = idx >> 3, c = (idx & 7) * 4;
            float4 v = *(const float4*)(Ab + row * Dn + kk + c);
            as[row][c + 0] = v.x; as[row][c + 1] = v.y;
            as[row][c + 2] = v.z; as[row][c + 3] = v.w;
        }
        __syncthreads();
#pragma unroll
        for (int d = 0; d < KC; d++) {
            float aq[4], aa[8];
#pragma unroll
            for (int i = 0; i < 4; i++) aq[i] = qs[ty * 4 + i][d];
#pragma unroll
            for (int j = 0; j < 8; j++) aa[j] = as[tx * 8 + j][d];
#pragma unroll
            for (int i = 0; i < 4; i++)
#pragma unroll
                for (int j = 0; j < 8; j++)
                    acc[i][j] = fmaf(aq[i], aa[j], acc[i][j]);
        }
    }

    const int nv = nodeNum[b];
#pragma unroll
    for (int i = 0; i < 4; i++) {
        int q = ty * 4 + i;
        size_t off = ((size_t)(b * Qn + q)) * Nn + n0 + tx * 8;
        *(float4*)(logits + off)     = make_float4(acc[i][0], acc[i][1], acc[i][2], acc[i][3]);
        *(float4*)(logits + off + 4) = make_float4(acc[i][4], acc[i][5], acc[i][6], acc[i][7]);

        float m = NEGF;
#pragma unroll
        for (int j = 0; j < 8; j++)
            if (n0 + tx * 8 + j < nv) m = fmaxf(m, acc[i][j]);
        float s = 0.f;
#pragma unroll
        for (int j = 0; j < 8; j++)
            if (n0 + tx * 8 + j < nv) s += __expf(acc[i][j] - m);
        redm[q][tx] = m;
        reds[q][tx] = s;
    }
    __syncthreads();
    if (tid < Qn) {
        int q = tid;
        float M = NEGF;
#pragma unroll
        for (int t = 0; t < 16; t++) M = fmaxf(M, redm[q][t]);
        float S = 0.f;
#pragma unroll
        for (int t = 0; t < 16; t++) {
            // if redm==NEGF, reds==0 so the term contributes 0 regardless
            S += reds[q][t] * __expf(redm[q][t] - M);
        }
        pmax[((size_t)(b * Qn + q)) * NTILES + tile] = M;
        psum[((size_t)(b * Qn + q)) * NTILES + tile] = S;
    }
}

// ---------------------------------------------------------------------------
// K2: combine the 128 per-tile partials of each (b,q) row -> M, 1/L
// ---------------------------------------------------------------------------
__global__ __launch_bounds__(64) void k_rows(
    const float* __restrict__ pmax, const float* __restrict__ psum,
    float* __restrict__ Mrow, float* __restrict__ invL)
{
    const int row = blockIdx.x;        // b*Q + q, 1024 rows
    const int t = threadIdx.x;         // 64 lanes
    const float* pm = pmax + (size_t)row * NTILES;
    const float* ps = psum + (size_t)row * NTILES;
    float m0 = pm[t], m1 = pm[t + 64];
    float s0 = ps[t], s1 = ps[t + 64];
    float m = fmaxf(m0, m1);
#pragma unroll
    for (int o = 32; o >= 1; o >>= 1) m = fmaxf(m, __shfl_xor(m, o, 64));
    float s = s0 * __expf(m0 - m) + s1 * __expf(m1 - m);
#pragma unroll
    for (int o = 32; o >= 1; o >>= 1) s += __shfl_xor(s, o, 64);
    if (t == 0) { Mrow[row] = m; invL[row] = 1.0f / s; }
}

// ---------------------------------------------------------------------------
// K3: p = exp(l - M) * invL (masked) -> prob_soft; then res += P @ A tile.
// ---------------------------------------------------------------------------
__global__ __launch_bounds__(256) void k_pv(
    const float* __restrict__ A,       // [B,N,D]
    const int*   __restrict__ nodeNum,
    const float* __restrict__ logits,
    const float* __restrict__ Mrow, const float* __restrict__ invL,
    float* __restrict__ soft,          // [B,Q,N]
    float* __restrict__ res)           // [B,Q,D], pre-zeroed
{
    const int b = blockIdx.y, tile = blockIdx.x;
    const int n0 = tile * NT;
    const int tid = threadIdx.x;
    const int tx = tid & 15, ty = tid >> 4;

    __shared__ float ps[Qn][NT + 1];   // 64 x 129
    __shared__ float at[KC][Dn + 1];   // 32 x 129
    __shared__ float Ms[Qn], Ls[Qn];

    if (tid < Qn) {
        int row = b * Qn + tid;
        Ms[tid] = Mrow[row];
        Ls[tid] = invL[row];
    }
    __syncthreads();

    const int nv = nodeNum[b];
#pragma unroll
    for (int it = 0; it < 4; it++) {
        int q = it * 16 + ty;
        size_t off = ((size_t)(b * Qn + q)) * Nn + n0 + tx * 8;
        float4 v0 = *(const float4*)(logits + off);
        float4 v1 = *(const float4*)(logits + off + 4);
        float l[8] = {v0.x, v0.y, v0.z, v0.w, v1.x, v1.y, v1.z, v1.w};
        float p[8];
        float mq = Ms[q], iq = Ls[q];
#pragma unroll
        for (int j = 0; j < 8; j++) {
            int n = n0 + tx * 8 + j;
            p[j] = (n < nv) ? __expf(l[j] - mq) * iq : 0.f;
            ps[q][tx * 8 + j] = p[j];
        }
        *(float4*)(soft + off)     = make_float4(p[0], p[1], p[2], p[3]);
        *(float4*)(soft + off + 4) = make_float4(p[4], p[5], p[6], p[7]);
    }

    float acc[4][8];
#pragma unroll
    for (int i = 0; i < 4; i++)
#pragma unroll
        for (int j = 0; j < 8; j++) acc[i][j] = 0.f;

    const float* Ab = A + (size_t)b * Nn * Dn + (size_t)n0 * Dn;
    for (int nc = 0; nc < NT; nc += KC) {
        __syncthreads();   // first iter: also fences the ps[] writes above
#pragma unroll
        for (int t = 0; t < 4; t++) {
            int idx = tid + t * 256;
            int row = idx >> 5, c = (idx & 31) * 4;
            float4 v = *(const float4*)(Ab + (size_t)(nc + row) * Dn + c);
            at[row][c + 0] = v.x; at[row][c + 1] = v.y;
            at[row][c + 2] = v.z; at[row][c + 3] = v.w;
        }
        __syncthreads();
#pragma unroll
        for (int nl = 0; nl < KC; nl++) {
            float aq[4], aa[8];
#pragma unroll
            for (int i = 0; i < 4; i++) aq[i] = ps[ty * 4 + i][nc + nl];
#pragma unroll
            for (int j = 0; j < 8; j++) aa[j] = at[nl][tx * 8 + j];
#pragma unroll
            for (int i = 0; i < 4; i++)
#pragma unroll
                for (int j = 0; j < 8; j++)
                    acc[i][j] = fmaf(aq[i], aa[j], acc[i][j]);
        }
    }

#pragma unroll
    for (int i = 0; i < 4; i++) {
        int q = ty * 4 + i;
        float* rp = res + ((size_t)(b * Qn + q)) * Dn + tx * 8;
#pragma unroll
        for (int j = 0; j < 8; j++) atomicAdd(rp + j, acc[i][j]);
    }
}

extern "C" void kernel_launch(void* const* d_in, const int* in_sizes, int n_in,
                              void* d_out, int out_size, void* d_ws, size_t ws_size,
                              hipStream_t stream) {
    const float* qv = (const float*)d_in[0];
    const float* A  = (const float*)d_in[1];
    const int*   nn = (const int*)d_in[2];

    float* out    = (float*)d_out;
    float* res    = out;             // [B,Q,D]
    float* soft   = out + SOFT_OFF;  // [B,Q,N]
    float* logits = out + LOG_OFF;   // [B,Q,N]

    float* ws   = (float*)d_ws;
    float* pmax = ws;                          // 131072 floats
    float* psum = ws + (size_t)Bn * Qn * NTILES;      // 131072
    float* Mrow = ws + (size_t)2 * Bn * Qn * NTILES;  // 1024
    float* invL = Mrow + Bn * Qn;                     // 1024

    // res_vector accumulated via atomics -> zero it (d_out poisoned 0xAA)
    hipMemsetAsync(res, 0, (size_t)RES_ELEMS * sizeof(float), stream);

    dim3 grid(NTILES, Bn), blk(256);
    k_logits<<<grid, blk, 0, stream>>>(qv, A, nn, logits, pmax, psum);
    k_rows<<<Bn * Qn, 64, 0, stream>>>(pmax, psum, Mrow, invL);
    k_pv<<<grid, blk, 0, stream>>>(A, nn, logits, Mrow, invL, soft, res);
}

// Round 2
// 407.174 us; speedup vs baseline: 2.0684x; 2.0684x over previous
//
#include <hip/hip_runtime.h>
#include <math.h>

// Problem constants
#define Bn 16
#define Qn 64
#define Nn 16384
#define Dn 128
#define NT 128                  // n-tile (k_logits block / k_pv subtile)
#define NTILES (Nn / NT)        // 128
#define KC 32                   // k-chunk
#define NCHUNK 512              // n per k_pv block
#define NCHUNKS (Nn / NCHUNK)   // 32

// Output layout (concat in reference return order)
#define RES_ELEMS  (Bn * Qn * Dn)      // 131072
#define SOFT_OFF   (RES_ELEMS)
#define LOG_OFF    (RES_ELEMS + Bn * Qn * Nn)

#define NEGF (-3.4e38f)

// ---------------------------------------------------------------------------
// K1: logits = Q @ A^T for one (b, n-tile); write raw logits; masked per-tile
//     max / sumexp partials. Strided register tile: q = i*16+ty, n = j*16+tx
//     -> conflict-free LDS fragment reads (addresses stride 1 row == 1 bank).
// ---------------------------------------------------------------------------
__global__ __launch_bounds__(256) void k_logits(
    const float* __restrict__ qv,      // [B,Q,D]
    const float* __restrict__ A,       // [B,N,D]
    const int*   __restrict__ nodeNum, // [B]
    float* __restrict__ logits,        // [B,Q,N]
    float* __restrict__ pmax,          // [B*Q, NTILES]
    float* __restrict__ psum)          // [B*Q, NTILES]
{
    const int b = blockIdx.y, tile = blockIdx.x;
    const int n0 = tile * NT;
    const int tid = threadIdx.x;
    const int tx = tid & 15, ty = tid >> 4;

    __shared__ float qs[Qn][KC + 1];   // 64 x 33
    __shared__ float as[NT][KC + 1];   // 128 x 33
    __shared__ float redm[Qn][17];
    __shared__ float reds[Qn][17];

    float acc[4][8];
#pragma unroll
    for (int i = 0; i < 4; i++)
#pragma unroll
        for (int j = 0; j < 8; j++) acc[i][j] = 0.f;

    const float* qb = qv + (size_t)b * Qn * Dn;
    const float* Ab = A  + (size_t)b * Nn * Dn + (size_t)n0 * Dn;

    for (int kk = 0; kk < Dn; kk += KC) {
        __syncthreads();
#pragma unroll
        for (int t = 0; t < 2; t++) {
            int idx = tid + t * 256;
            int row = idx >> 3, c = (idx & 7) * 4;
            float4 v = *(const float4*)(qb + row * Dn + kk + c);
            qs[row][c + 0] = v.x; qs[row][c + 1] = v.y;
            qs[row][c + 2] = v.z; qs[row][c + 3] = v.w;
        }
#pragma unroll
        for (int t = 0; t < 4; t++) {
            int idx = tid + t * 256;
            int row = idx >> 3, c = (idx & 7) * 4;
            float4 v = *(const float4*)(Ab + row * Dn + kk + c);
            as[row][c + 0] = v.x; as[row][c + 1] = v.y;
            as[row][c + 2] = v.z; as[row][c + 3] = v.w;
        }
        __syncthreads();
#pragma unroll
        for (int d = 0; d < KC; d++) {
            float aq[4], aa[8];
#pragma unroll
            for (int i = 0; i < 4; i++) aq[i] = qs[i * 16 + ty][d];
#pragma unroll
            for (int j = 0; j < 8; j++) aa[j] = as[j * 16 + tx][d];
#pragma unroll
            for (int i = 0; i < 4; i++)
#pragma unroll
                for (int j = 0; j < 8; j++)
                    acc[i][j] = fmaf(aq[i], aa[j], acc[i][j]);
        }
    }

    const int nv = nodeNum[b];
#pragma unroll
    for (int i = 0; i < 4; i++) {
        int q = i * 16 + ty;
        size_t base = ((size_t)(b * Qn + q)) * Nn + n0;
        float m = NEGF;
        float s = 0.f;
#pragma unroll
        for (int j = 0; j < 8; j++) {
            int n = j * 16 + tx;
            logits[base + n] = acc[i][j];
            if (n0 + n < nv) m = fmaxf(m, acc[i][j]);
        }
#pragma unroll
        for (int j = 0; j < 8; j++) {
            int n = j * 16 + tx;
            if (n0 + n < nv) s += __expf(acc[i][j] - m);
        }
        redm[q][tx] = m;
        reds[q][tx] = s;
    }
    __syncthreads();
    if (tid < Qn) {
        int q = tid;
        float M = NEGF;
#pragma unroll
        for (int t = 0; t < 16; t++) M = fmaxf(M, redm[q][t]);
        float S = 0.f;
#pragma unroll
        for (int t = 0; t < 16; t++)
            S += reds[q][t] * __expf(redm[q][t] - M);
        pmax[((size_t)(b * Qn + q)) * NTILES + tile] = M;
        psum[((size_t)(b * Qn + q)) * NTILES + tile] = S;
    }
}

// ---------------------------------------------------------------------------
// K2: combine 128 per-tile partials per (b,q) row -> M, 1/L
// ---------------------------------------------------------------------------
__global__ __launch_bounds__(64) void k_rows(
    const float* __restrict__ pmax, const float* __restrict__ psum,
    float* __restrict__ Mrow, float* __restrict__ invL)
{
    const int row = blockIdx.x;
    const int t = threadIdx.x;
    const float* pm = pmax + (size_t)row * NTILES;
    const float* ps = psum + (size_t)row * NTILES;
    float m0 = pm[t], m1 = pm[t + 64];
    float s0 = ps[t], s1 = ps[t + 64];
    float m = fmaxf(m0, m1);
#pragma unroll
    for (int o = 32; o >= 1; o >>= 1) m = fmaxf(m, __shfl_xor(m, o, 64));
    float s = s0 * __expf(m0 - m) + s1 * __expf(m1 - m);
#pragma unroll
    for (int o = 32; o >= 1; o >>= 1) s += __shfl_xor(s, o, 64);
    if (t == 0) { Mrow[row] = m; invL[row] = 1.0f / s; }
}

// ---------------------------------------------------------------------------
// K3: per (b, 512-n chunk): p = exp(l-M)*invL -> prob_soft; res partial =
//     P @ A(chunk) into ws (NO atomics). Strided tile q=i*16+ty, d=j*16+tx.
// ---------------------------------------------------------------------------
__global__ __launch_bounds__(256) void k_pv(
    const float* __restrict__ A,       // [B,N,D]
    const int*   __restrict__ nodeNum,
    const float* __restrict__ logits,
    const float* __restrict__ Mrow, const float* __restrict__ invL,
    float* __restrict__ soft,          // [B,Q,N]
    float* __restrict__ partial)       // [NCHUNKS][B,Q,D]
{
    const int b = blockIdx.y, chunk = blockIdx.x;
    const int tid = threadIdx.x;
    const int tx = tid & 15, ty = tid >> 4;

    __shared__ float ps[Qn][NT + 1];   // 64 x 129
    __shared__ float at[KC][Dn + 1];   // 32 x 129
    __shared__ float Ms[Qn], Ls[Qn];

    if (tid < Qn) {
        int row = b * Qn + tid;
        Ms[tid] = Mrow[row];
        Ls[tid] = invL[row];
    }

    float acc[4][8];
#pragma unroll
    for (int i = 0; i < 4; i++)
#pragma unroll
        for (int j = 0; j < 8; j++) acc[i][j] = 0.f;

    const int nv = nodeNum[b];

    for (int st = 0; st < NCHUNK / NT; st++) {
        const int n0 = chunk * NCHUNK + st * NT;
        __syncthreads();   // ps reuse fence (and Ms/Ls on first iter)
#pragma unroll
        for (int it = 0; it < 4; it++) {
            int q = it * 16 + ty;
            size_t off = ((size_t)(b * Qn + q)) * Nn + n0 + tx * 8;
            float4 v0 = *(const float4*)(logits + off);
            float4 v1 = *(const float4*)(logits + off + 4);
            float l[8] = {v0.x, v0.y, v0.z, v0.w, v1.x, v1.y, v1.z, v1.w};
            float p[8];
            float mq = Ms[q], iq = Ls[q];
#pragma unroll
            for (int j = 0; j < 8; j++) {
                int n = n0 + tx * 8 + j;
                p[j] = (n < nv) ? __expf(l[j] - mq) * iq : 0.f;
                ps[q][tx * 8 + j] = p[j];
            }
            *(float4*)(soft + off)     = make_float4(p[0], p[1], p[2], p[3]);
            *(float4*)(soft + off + 4) = make_float4(p[4], p[5], p[6], p[7]);
        }

        const float* Ab = A + (size_t)b * Nn * Dn + (size_t)n0 * Dn;
        for (int nc = 0; nc < NT; nc += KC) {
            __syncthreads();  // at reuse fence; also fences ps writes (1st nc)
#pragma unroll
            for (int t = 0; t < 4; t++) {
                int idx = tid + t * 256;
                int row = idx >> 5, c = (idx & 31) * 4;
                float4 v = *(const float4*)(Ab + (size_t)(nc + row) * Dn + c);
                at[row][c + 0] = v.x; at[row][c + 1] = v.y;
                at[row][c + 2] = v.z; at[row][c + 3] = v.w;
            }
            __syncthreads();
#pragma unroll
            for (int nl = 0; nl < KC; nl++) {
                float aq[4], aa[8];
#pragma unroll
                for (int i = 0; i < 4; i++) aq[i] = ps[i * 16 + ty][nc + nl];
#pragma unroll
                for (int j = 0; j < 8; j++) aa[j] = at[nl][j * 16 + tx];
#pragma unroll
                for (int i = 0; i < 4; i++)
#pragma unroll
                    for (int j = 0; j < 8; j++)
                        acc[i][j] = fmaf(aq[i], aa[j], acc[i][j]);
            }
        }
    }

    float* pout = partial + (size_t)chunk * RES_ELEMS + (size_t)(b * Qn) * Dn;
#pragma unroll
    for (int i = 0; i < 4; i++) {
        int q = i * 16 + ty;
#pragma unroll
        for (int j = 0; j < 8; j++) {
            int d = j * 16 + tx;
            pout[q * Dn + d] = acc[i][j];
        }
    }
}

// ---------------------------------------------------------------------------
// K4: res = sum over 32 chunk-partials
// ---------------------------------------------------------------------------
__global__ __launch_bounds__(256) void k_red(
    const float* __restrict__ partial, float* __restrict__ res)
{
    int g = blockIdx.x * 256 + threadIdx.x;   // < RES_ELEMS
    float s = 0.f;
#pragma unroll
    for (int t = 0; t < NCHUNKS; t++)
        s += partial[(size_t)t * RES_ELEMS + g];
    res[g] = s;
}

extern "C" void kernel_launch(void* const* d_in, const int* in_sizes, int n_in,
                              void* d_out, int out_size, void* d_ws, size_t ws_size,
                              hipStream_t stream) {
    const float* qv = (const float*)d_in[0];
    const float* A  = (const float*)d_in[1];
    const int*   nn = (const int*)d_in[2];

    float* out    = (float*)d_out;
    float* res    = out;             // [B,Q,D]
    float* soft   = out + SOFT_OFF;  // [B,Q,N]
    float* logits = out + LOG_OFF;   // [B,Q,N]

    float* ws      = (float*)d_ws;
    float* pmax    = ws;                                   // 131072
    float* psum    = pmax + (size_t)Bn * Qn * NTILES;      // 131072
    float* Mrow    = psum + (size_t)Bn * Qn * NTILES;      // 1024
    float* invL    = Mrow + Bn * Qn;                       // 1024
    float* partial = invL + Bn * Qn;                       // 32 * 131072

    dim3 blk(256);
    k_logits<<<dim3(NTILES, Bn), blk, 0, stream>>>(qv, A, nn, logits, pmax, psum);
    k_rows<<<Bn * Qn, 64, 0, stream>>>(pmax, psum, Mrow, invL);
    k_pv<<<dim3(NCHUNKS, Bn), blk, 0, stream>>>(A, nn, logits, Mrow, invL, soft, partial);
    k_red<<<RES_ELEMS / 256, blk, 0, stream>>>(partial, res);
}

// Round 3
// 296.118 us; speedup vs baseline: 2.8441x; 1.3750x over previous
//
#include <hip/hip_runtime.h>
#include <math.h>

// Problem constants
#define Bn 16
#define Qn 64
#define Nn 16384
#define Dn 128
#define NT 128                  // n-tile per k_logits block
#define NTILES (Nn / NT)        // 128
#define NCHUNK 512              // n per k_pv block
#define NCHUNKS (Nn / NCHUNK)   // 32

#define RES_ELEMS  (Bn * Qn * Dn)      // 131072
#define SOFT_OFF   (RES_ELEMS)
#define LOG_OFF    (RES_ELEMS + Bn * Qn * Nn)

#define NEGF (-3.4e38f)

typedef __attribute__((ext_vector_type(8))) short short8;   // 8 bf16 (4 VGPRs)
typedef float f32x4 __attribute__((ext_vector_type(4)));    // MFMA accumulator

typedef union { unsigned int u[4]; short8 v; } pk8;

// round-to-nearest-even fp32 -> bf16 (inputs are finite randn; no NaN path)
__device__ __forceinline__ unsigned short f2bf(float x) {
    unsigned int u = __float_as_uint(x);
    return (unsigned short)((u + 0x7FFF + ((u >> 16) & 1)) >> 16);
}
__device__ __forceinline__ float bf2f(unsigned short h) {
    return __uint_as_float(((unsigned int)h) << 16);
}

// ---------------------------------------------------------------------------
// K1: logits = Q @ A^T via split-bf16 MFMA (hi*hi + hi*lo + lo*hi == fp32-ish)
// Block: 256 thr = 4 waves. Tile M=64 q x N=128 n, K=128 in 2 chunks of 64.
// Wave w owns n-subtiles {2w, 2w+1}; per wave 4m x 2n accumulators.
// Epilogue: acc -> LDS (fp32) -> coalesced float4 logits stores + masked stats.
// ---------------------------------------------------------------------------
__global__ __launch_bounds__(256) void k_logits(
    const float* __restrict__ qv, const float* __restrict__ A,
    const int* __restrict__ nodeNum,
    float* __restrict__ logits,
    float* __restrict__ pmax, float* __restrict__ psum)
{
    const int b = blockIdx.y, tile = blockIdx.x;
    const int n0 = tile * NT;
    const int tid = threadIdx.x;
    const int lane = tid & 63, wave = tid >> 6;
    const int qd = lane >> 4, cc = lane & 15;   // quad, col-in-16

    // staging (phase 1): QHI/QLO 64x72 u16, AHI/ALO 128x72 u16 = 55296 B
    // alias (phase 2): CB 64x132 f32 (33792 B), REDM/REDS 64x17 f32
    __shared__ __align__(16) unsigned char smem[55296];
    unsigned short* QHI = (unsigned short*)smem;
    unsigned short* QLO = QHI + 64 * 72;
    unsigned short* AHI = QLO + 64 * 72;
    unsigned short* ALO = AHI + 128 * 72;
    float* CB   = (float*)smem;            // [64][132]
    float* REDM = ((float*)smem) + 64 * 132;
    float* REDS = REDM + 64 * 17;

    f32x4 acc[4][2];
#pragma unroll
    for (int mi = 0; mi < 4; mi++)
#pragma unroll
        for (int ni = 0; ni < 2; ni++) acc[mi][ni] = 0.f;

    const float* qb = qv + (size_t)b * Qn * Dn;
    const float* Ab = A  + (size_t)b * Nn * Dn + (size_t)n0 * Dn;

    for (int kk = 0; kk < Dn; kk += 64) {
        __syncthreads();
        // stage Q slab 64x64: 1024 float4 units
#pragma unroll
        for (int t = 0; t < 4; t++) {
            int u = tid + t * 256;
            int row = u >> 4, c4 = u & 15;
            float4 v = *(const float4*)(qb + row * Dn + kk + c4 * 4);
            ushort4 hi, lo;
            hi.x = f2bf(v.x); lo.x = f2bf(v.x - bf2f(hi.x));
            hi.y = f2bf(v.y); lo.y = f2bf(v.y - bf2f(hi.y));
            hi.z = f2bf(v.z); lo.z = f2bf(v.z - bf2f(hi.z));
            hi.w = f2bf(v.w); lo.w = f2bf(v.w - bf2f(hi.w));
            *(ushort4*)(QHI + row * 72 + c4 * 4) = hi;
            *(ushort4*)(QLO + row * 72 + c4 * 4) = lo;
        }
        // stage A slab 128x64: 2048 float4 units
#pragma unroll
        for (int t = 0; t < 8; t++) {
            int u = tid + t * 256;
            int row = u >> 4, c4 = u & 15;
            float4 v = *(const float4*)(Ab + row * Dn + kk + c4 * 4);
            ushort4 hi, lo;
            hi.x = f2bf(v.x); lo.x = f2bf(v.x - bf2f(hi.x));
            hi.y = f2bf(v.y); lo.y = f2bf(v.y - bf2f(hi.y));
            hi.z = f2bf(v.z); lo.z = f2bf(v.z - bf2f(hi.z));
            hi.w = f2bf(v.w); lo.w = f2bf(v.w - bf2f(hi.w));
            *(ushort4*)(AHI + row * 72 + c4 * 4) = hi;
            *(ushort4*)(ALO + row * 72 + c4 * 4) = lo;
        }
        __syncthreads();
#pragma unroll
        for (int ks = 0; ks < 64; ks += 32) {
            const int ko = ks + qd * 8;   // u16 col of this lane's k-octet
            short8 qh[4], ql[4], ah[2], al[2];
#pragma unroll
            for (int mi = 0; mi < 4; mi++) {
                int r = mi * 16 + cc;
                qh[mi] = *(const short8*)(QHI + r * 72 + ko);
                ql[mi] = *(const short8*)(QLO + r * 72 + ko);
            }
#pragma unroll
            for (int ni = 0; ni < 2; ni++) {
                int r = (wave * 2 + ni) * 16 + cc;
                ah[ni] = *(const short8*)(AHI + r * 72 + ko);
                al[ni] = *(const short8*)(ALO + r * 72 + ko);
            }
#pragma unroll
            for (int mi = 0; mi < 4; mi++)
#pragma unroll
                for (int ni = 0; ni < 2; ni++) {
                    acc[mi][ni] = __builtin_amdgcn_mfma_f32_16x16x32_bf16(
                        ql[mi], ah[ni], acc[mi][ni], 0, 0, 0);
                    acc[mi][ni] = __builtin_amdgcn_mfma_f32_16x16x32_bf16(
                        qh[mi], al[ni], acc[mi][ni], 0, 0, 0);
                    acc[mi][ni] = __builtin_amdgcn_mfma_f32_16x16x32_bf16(
                        qh[mi], ah[ni], acc[mi][ni], 0, 0, 0);
                }
        }
    }

    __syncthreads();   // staging dead; alias LDS as CB
    // C-layout: col = lane&15 (n), row = quad*4 + reg (q)
#pragma unroll
    for (int mi = 0; mi < 4; mi++)
#pragma unroll
        for (int ni = 0; ni < 2; ni++)
#pragma unroll
            for (int r = 0; r < 4; r++) {
                int q = mi * 16 + qd * 4 + r;
                int n = (wave * 2 + ni) * 16 + cc;
                CB[q * 132 + n] = acc[mi][ni][r];
            }
    __syncthreads();

    const int nv = nodeNum[b];
    // coalesced logits store
#pragma unroll
    for (int t = 0; t < 8; t++) {
        int u = tid + t * 256;
        int q = u >> 5, ng = u & 31;
        float4 v = *(const float4*)(CB + q * 132 + ng * 4);
        *(float4*)(logits + ((size_t)(b * Qn + q)) * Nn + n0 + ng * 4) = v;
    }
    // masked per-tile stats
#pragma unroll
    for (int t = 0; t < 4; t++) {
        int u = tid + t * 256;
        int q = u >> 4, c = u & 15;
        const float* base = CB + q * 132 + c * 8;
        float m = NEGF;
#pragma unroll
        for (int j = 0; j < 8; j++)
            if (n0 + c * 8 + j < nv) m = fmaxf(m, base[j]);
        float s = 0.f;
#pragma unroll
        for (int j = 0; j < 8; j++)
            if (n0 + c * 8 + j < nv) s += __expf(base[j] - m);
        REDM[q * 17 + c] = m;
        REDS[q * 17 + c] = s;
    }
    __syncthreads();
    if (tid < Qn) {
        int q = tid;
        float M = NEGF;
#pragma unroll
        for (int t = 0; t < 16; t++) M = fmaxf(M, REDM[q * 17 + t]);
        float S = 0.f;
#pragma unroll
        for (int t = 0; t < 16; t++)
            S += REDS[q * 17 + t] * __expf(REDM[q * 17 + t] - M);
        pmax[((size_t)(b * Qn + q)) * NTILES + tile] = M;
        psum[((size_t)(b * Qn + q)) * NTILES + tile] = S;
    }
}

// ---------------------------------------------------------------------------
// K2: combine 128 per-tile partials per (b,q) row -> M, 1/L
// ---------------------------------------------------------------------------
__global__ __launch_bounds__(64) void k_rows(
    const float* __restrict__ pmax, const float* __restrict__ psum,
    float* __restrict__ Mrow, float* __restrict__ invL)
{
    const int row = blockIdx.x;
    const int t = threadIdx.x;
    const float* pm = pmax + (size_t)row * NTILES;
    const float* ps = psum + (size_t)row * NTILES;
    float m0 = pm[t], m1 = pm[t + 64];
    float s0 = ps[t], s1 = ps[t + 64];
    float m = fmaxf(m0, m1);
#pragma unroll
    for (int o = 32; o >= 1; o >>= 1) m = fmaxf(m, __shfl_xor(m, o, 64));
    float s = s0 * __expf(m0 - m) + s1 * __expf(m1 - m);
#pragma unroll
    for (int o = 32; o >= 1; o >>= 1) s += __shfl_xor(s, o, 64);
    if (t == 0) { Mrow[row] = m; invL[row] = 1.0f / s; }
}

// ---------------------------------------------------------------------------
// K3: softmax (p -> prob_soft fp32 + bf16 P-tile in LDS) then P @ A via MFMA.
// A staged as bf16 (n,n+1)-pair-packed dwords TMP2[n/2][d] so the B-fragment
// (contraction dim n lane-contiguous) is 4x ds_read_b32 per tile.
// Per (b, 512-n chunk): 16 slabs of 32 n; wave w owns d-subtiles {2w, 2w+1}.
// ---------------------------------------------------------------------------
__global__ __launch_bounds__(256) void k_pv(
    const float* __restrict__ A, const int* __restrict__ nodeNum,
    const float* __restrict__ logits,
    const float* __restrict__ Mrow, const float* __restrict__ invL,
    float* __restrict__ soft, float* __restrict__ partial)
{
    const int b = blockIdx.y, chunk = blockIdx.x;
    const int tid = threadIdx.x;
    const int lane = tid & 63, wave = tid >> 6;
    const int qd = lane >> 4, cc = lane & 15;

    __shared__ __align__(16) unsigned short PS[64 * 40];   // P bf16 [q][32n], pitch 40
    __shared__ __align__(16) unsigned int  TMP2[16 * 132]; // A pairs [n2][128d], pitch 132
    __shared__ float MS[64], LS[64];

    if (tid < Qn) {
        MS[tid] = Mrow[b * Qn + tid];
        LS[tid] = invL[b * Qn + tid];
    }

    f32x4 acc[4][2];
#pragma unroll
    for (int mi = 0; mi < 4; mi++)
#pragma unroll
        for (int ni = 0; ni < 2; ni++) acc[mi][ni] = 0.f;

    const int nv = nodeNum[b];
    const float* Abase = A + (size_t)b * Nn * Dn;

    for (int s = 0; s < 16; s++) {
        const int n0 = chunk * NCHUNK + s * 32;
        __syncthreads();   // PS/TMP2 reuse fence (and MS/LS on first iter)

        // softmax: 64q x 32n = 512 float4-units of 4 n
#pragma unroll
        for (int t = 0; t < 2; t++) {
            int u = tid + t * 256;
            int q = u >> 3, ng = u & 7;
            size_t go = ((size_t)(b * Qn + q)) * Nn + n0 + ng * 4;
            float4 l4 = *(const float4*)(logits + go);
            float mq = MS[q], iq = LS[q];
            int nb = n0 + ng * 4;
            float4 p;
            p.x = (nb + 0 < nv) ? __expf(l4.x - mq) * iq : 0.f;
            p.y = (nb + 1 < nv) ? __expf(l4.y - mq) * iq : 0.f;
            p.z = (nb + 2 < nv) ? __expf(l4.z - mq) * iq : 0.f;
            p.w = (nb + 3 < nv) ? __expf(l4.w - mq) * iq : 0.f;
            *(float4*)(soft + go) = p;
            unsigned int d0 = (unsigned)f2bf(p.x) | ((unsigned)f2bf(p.y) << 16);
            unsigned int d1 = (unsigned)f2bf(p.z) | ((unsigned)f2bf(p.w) << 16);
            unsigned int* dst = (unsigned int*)(PS + q * 40 + ng * 4);
            dst[0] = d0; dst[1] = d1;
        }
        // stage A slab 32n x 128d as (n,n+1) bf16 pairs: 512 uint4-units
#pragma unroll
        for (int t = 0; t < 2; t++) {
            int u = tid + t * 256;
            int n2 = u >> 5, db = u & 31;
            const float* r0 = Abase + (size_t)(n0 + n2 * 2) * Dn + db * 4;
            float4 a0 = *(const float4*)r0;          // n even
            float4 a1 = *(const float4*)(r0 + Dn);   // n odd
            uint4 w;
            w.x = (unsigned)f2bf(a0.x) | ((unsigned)f2bf(a1.x) << 16);
            w.y = (unsigned)f2bf(a0.y) | ((unsigned)f2bf(a1.y) << 16);
            w.z = (unsigned)f2bf(a0.z) | ((unsigned)f2bf(a1.z) << 16);
            w.w = (unsigned)f2bf(a0.w) | ((unsigned)f2bf(a1.w) << 16);
            *(uint4*)(TMP2 + n2 * 132 + db * 4) = w;
        }
        __syncthreads();

        short8 pf[4];
#pragma unroll
        for (int mi = 0; mi < 4; mi++)
            pf[mi] = *(const short8*)(PS + (mi * 16 + cc) * 40 + qd * 8);
#pragma unroll
        for (int ni = 0; ni < 2; ni++) {
            int d = (wave * 2 + ni) * 16 + cc;
            pk8 bfr;
#pragma unroll
            for (int j = 0; j < 4; j++)
                bfr.u[j] = TMP2[(qd * 4 + j) * 132 + d];
#pragma unroll
            for (int mi = 0; mi < 4; mi++)
                acc[mi][ni] = __builtin_amdgcn_mfma_f32_16x16x32_bf16(
                    pf[mi], bfr.v, acc[mi][ni], 0, 0, 0);
        }
    }

    float* pout = partial + (size_t)chunk * RES_ELEMS + (size_t)(b * Qn) * Dn;
#pragma unroll
    for (int mi = 0; mi < 4; mi++)
#pragma unroll
        for (int ni = 0; ni < 2; ni++)
#pragma unroll
            for (int r = 0; r < 4; r++) {
                int q = mi * 16 + qd * 4 + r;
                int d = (wave * 2 + ni) * 16 + cc;
                pout[q * Dn + d] = acc[mi][ni][r];
            }
}

// ---------------------------------------------------------------------------
// K4: res = sum over 32 chunk-partials
// ---------------------------------------------------------------------------
__global__ __launch_bounds__(256) void k_red(
    const float* __restrict__ partial, float* __restrict__ res)
{
    int g = blockIdx.x * 256 + threadIdx.x;
    float s = 0.f;
#pragma unroll
    for (int t = 0; t < NCHUNKS; t++)
        s += partial[(size_t)t * RES_ELEMS + g];
    res[g] = s;
}

extern "C" void kernel_launch(void* const* d_in, const int* in_sizes, int n_in,
                              void* d_out, int out_size, void* d_ws, size_t ws_size,
                              hipStream_t stream) {
    const float* qv = (const float*)d_in[0];
    const float* A  = (const float*)d_in[1];
    const int*   nn = (const int*)d_in[2];

    float* out    = (float*)d_out;
    float* res    = out;
    float* soft   = out + SOFT_OFF;
    float* logits = out + LOG_OFF;

    float* ws      = (float*)d_ws;
    float* pmax    = ws;
    float* psum    = pmax + (size_t)Bn * Qn * NTILES;
    float* Mrow    = psum + (size_t)Bn * Qn * NTILES;
    float* invL    = Mrow + Bn * Qn;
    float* partial = invL + Bn * Qn;

    dim3 blk(256);
    k_logits<<<dim3(NTILES, Bn), blk, 0, stream>>>(qv, A, nn, logits, pmax, psum);
    k_rows<<<Bn * Qn, 64, 0, stream>>>(pmax, psum, Mrow, invL);
    k_pv<<<dim3(NCHUNKS, Bn), blk, 0, stream>>>(A, nn, logits, Mrow, invL, soft, partial);
    k_red<<<RES_ELEMS / 256, blk, 0, stream>>>(partial, res);
}